// Round 10
// baseline (204.731 us; speedup 1.0000x reference)
//
#include <hip/hip_runtime.h>
#include <hip/hip_bf16.h>
#include <math.h>

#define B_    16
#define M_    128
#define T_    2048
#define H_    512
#define TOUT_ 2049

typedef unsigned short u16;
typedef unsigned int   u32;
typedef __bf16 bf16x8 __attribute__((ext_vector_type(8)));
typedef float  f32x16 __attribute__((ext_vector_type(16)));
typedef float  f32x4  __attribute__((ext_vector_type(4)));
typedef u32    u32x4  __attribute__((ext_vector_type(4)));
typedef u32    u32x2  __attribute__((ext_vector_type(2)));

// ws layout (float units):
#define A_OFF     0                       // fp32 Ao only [128][128]
#define C_OFF     16384                   // c[3][128]
#define MEAN_OFF  16896                   // meanv [2048]
#define AQKBF_OFF 19200                   // u16 [256][128] = 16384 fl
#define AOBF_OFF  35584                   // u16 [128][128] = 8192 fl
#define QT_OFF    43776
#define KT_OFF    (43776 + 2097152)
#define VB_OFF    (43776 + 2 * 2097152)

static __device__ __forceinline__ u16 f2bf(float f) {
  u32 u = __float_as_uint(f);
  u = (u + 0x7FFFu + ((u >> 16) & 1u)) >> 16;
  return (u16)u;
}
static __device__ __forceinline__ u32 pk2(float lo, float hi) {
  __hip_bfloat162 h = __float22bfloat162_rn(float2{lo, hi});
  u32 r;
  __builtin_memcpy(&r, &h, 4);
  return r;
}
static __device__ __forceinline__ bf16x8 ldfrag(const u16* p) {
  return __builtin_bit_cast(bf16x8, *(const u32x4*)p);
}
static __device__ __forceinline__ float ex2(float x) {
#if __has_builtin(__builtin_amdgcn_exp2f)
  return __builtin_amdgcn_exp2f(x);  // v_exp_f32 = 2^x
#else
  return exp2f(x);
#endif
}
// direct HBM/L2 -> LDS DMA, 16 B per lane; lds dest = uniform base + lane*16
static __device__ __forceinline__ void g2l16(const u16* g, u16* l) {
  __builtin_amdgcn_global_load_lds(
      (const __attribute__((address_space(1))) u32*)(const void*)g,
      (__attribute__((address_space(3))) u32*)(void*)l, 16, 0, 0);
}

// ---------------------------------------------------------------------------
// fuse: blocks [0,384) = weight fusion; blocks [384, 384+2048) = value cast
// (written FRAG-MAJOR for attn) + windowed mean.
__global__ __launch_bounds__(128) void fuse_weights_all(
    const float* __restrict__ W1q, const float* __restrict__ b1q,
    const float* __restrict__ W2q, const float* __restrict__ b2q,
    const float* __restrict__ W1k, const float* __restrict__ b1k,
    const float* __restrict__ W2k, const float* __restrict__ b2k,
    const float* __restrict__ W1o, const float* __restrict__ b1o,
    const float* __restrict__ W2o, const float* __restrict__ b2o,
    float* __restrict__ A, float* __restrict__ c,
    u16* __restrict__ Aqk_bf, u16* __restrict__ Ao_bf,
    const float* __restrict__ value, u16* __restrict__ vb,
    float* __restrict__ meanv) {
  __shared__ float w2row[H_];
  int tid = threadIdx.x;

  if (blockIdx.x >= 384) {
    int bm = blockIdx.x - 384;
    int b2 = bm >> 7, m = bm & 127;
    int mt2 = m >> 5, m31 = m & 31;
    float* red = w2row;
    const float* row = value + (size_t)bm * T_;
    int i0 = tid * 16;
    float4 a0 = *(const float4*)(row + i0);
    float4 a1 = *(const float4*)(row + i0 + 4);
    float4 a2 = *(const float4*)(row + i0 + 8);
    float4 a3 = *(const float4*)(row + i0 + 12);
    u32x4 o0 = {pk2(a0.x, a0.y), pk2(a0.z, a0.w), pk2(a1.x, a1.y), pk2(a1.z, a1.w)};
    u32x4 o1 = {pk2(a2.x, a2.y), pk2(a2.z, a2.w), pk2(a3.x, a3.y), pk2(a3.z, a3.w)};
    // frag-major V: chunk = (b*64+tb)*8 + mt*2 + s2; within: (hb*32+m31)*8
#pragma unroll
    for (int cc = 0; cc < 2; ++cc) {
      int t8 = i0 + cc * 8;
      int tb = t8 >> 5, tw = t8 & 31;
      int s2 = tw >> 4, hb2 = (tw >> 3) & 1;
      size_t off = ((size_t)((b2 * 64 + tb) * 8 + mt2 * 2 + s2)) * 512
                 + (hb2 * 32 + m31) * 8;
      *(u32x4*)&vb[off] = cc ? o1 : o0;
    }
    float vals[16] = {a0.x, a0.y, a0.z, a0.w, a1.x, a1.y, a1.z, a1.w,
                      a2.x, a2.y, a2.z, a2.w, a3.x, a3.y, a3.z, a3.w};
    float s = 0.f;
#pragma unroll
    for (int j = 0; j < 16; ++j) {
      int idx = i0 + j;
      if (idx >= 33 && idx < T_ - 1) s += vals[j];
    }
    red[tid] = s;
    __syncthreads();
    for (int st = 64; st > 0; st >>= 1) {
      if (tid < st) red[tid] += red[tid + st];
      __syncthreads();
    }
    if (tid == 0) meanv[bm] = red[0] * (1.f / 2014.f);
    return;
  }

  int which = blockIdx.x >> 7;
  int o = blockIdx.x & 127;
  const float* W1 = which == 0 ? W1q : which == 1 ? W1k : W1o;
  const float* b1 = which == 0 ? b1q : which == 1 ? b1k : b1o;
  const float* W2 = which == 0 ? W2q : which == 1 ? W2k : W2o;
  const float* b2 = which == 0 ? b2q : which == 1 ? b2k : b2o;
  int m = tid;
  for (int h = m; h < H_; h += 128) w2row[h] = W2[o * H_ + h];
  __syncthreads();
  float acc = 0.f;
#pragma unroll 8
  for (int h = 0; h < H_; ++h) acc = fmaf(w2row[h], W1[h * M_ + m], acc);
  u16 ab = f2bf(acc);
  if (which == 0)      Aqk_bf[o * 128 + m] = ab;
  else if (which == 1) Aqk_bf[(128 + o) * 128 + m] = ab;
  else               { Ao_bf[o * 128 + m] = ab; A[o * M_ + m] = acc; }
  if (m < 64) {
    float cc = 0.f;
    for (int h = m; h < H_; h += 64) cc = fmaf(w2row[h], b1[h], cc);
#pragma unroll
    for (int off = 32; off > 0; off >>= 1) cc += __shfl_down(cc, off, 64);
    if (m == 0) c[which * 128 + o] = cc + b2[o];
  }
}

// ---------------------------------------------------------------------------
// prep: 512 blocks, q/k MLP. Outputs qT/kT in FRAG-MAJOR layout:
//   chunk(b, kb=t>>5, s) at ((b*64+kb)*8+s)*512 + (hb*32 + (t&31))*8
//   holding K[t][o = (l>>5)*8 + s*16 + j] per lane l.
// q outputs pre-scaled by log2(e).
#define XS 68

__global__ __launch_bounds__(256) void prep_kernel(
    const float* __restrict__ pattern, const u16* __restrict__ Aqk_bf,
    const float* __restrict__ cqk, u16* __restrict__ qT, u16* __restrict__ kT) {
  __shared__ alignas(16) float xsf[128 * XS];
  int bx = blockIdx.x;
  int tid = threadIdx.x;

  int b = bx >> 5;
  int t0 = (bx & 31) * 64;
  int lane = tid & 63;
  int wv = tid >> 6;
  int l31 = lane & 31;
  int lh8 = (lane >> 5) * 8;

  bf16x8 afr[2][8];
#pragma unroll
  for (int i = 0; i < 2; ++i) {
    const u16* ap = Aqk_bf + ((2 * wv + i) * 32 + l31) * 128 + lh8;
#pragma unroll
    for (int s = 0; s < 8; ++s) afr[i][s] = ldfrag(ap + 16 * s);
  }

#pragma unroll
  for (int rep = 0; rep < 8; ++rep) {
    int m = rep * 16 + (tid >> 4);
    int tc = (tid & 15) * 4;
    float4 v = *(const float4*)&pattern[(size_t)(b * M_ + m) * T_ + t0 + tc];
    *(float4*)&xsf[m * XS + tc] = v;
  }
  __syncthreads();

  bf16x8 bfr[2][8];
#pragma unroll
  for (int tt = 0; tt < 2; ++tt) {
#pragma unroll
    for (int s = 0; s < 8; ++s) {
      float v0 = xsf[(s * 16 + lh8 + 0) * XS + tt * 32 + l31];
      float v1 = xsf[(s * 16 + lh8 + 1) * XS + tt * 32 + l31];
      float v2 = xsf[(s * 16 + lh8 + 2) * XS + tt * 32 + l31];
      float v3 = xsf[(s * 16 + lh8 + 3) * XS + tt * 32 + l31];
      float v4 = xsf[(s * 16 + lh8 + 4) * XS + tt * 32 + l31];
      float v5 = xsf[(s * 16 + lh8 + 5) * XS + tt * 32 + l31];
      float v6 = xsf[(s * 16 + lh8 + 6) * XS + tt * 32 + l31];
      float v7 = xsf[(s * 16 + lh8 + 7) * XS + tt * 32 + l31];
      u32x4 p = {pk2(v0, v1), pk2(v2, v3), pk2(v4, v5), pk2(v6, v7)};
      bfr[tt][s] = __builtin_bit_cast(bf16x8, p);
    }
  }
  __syncthreads();  // xsf dead -> obuf

  u16* obuf = (u16*)xsf;  // [64 t][258 o]
#pragma unroll
  for (int tt = 0; tt < 2; ++tt) {
#pragma unroll
    for (int i = 0; i < 2; ++i) {
      f32x16 acc;
#pragma unroll
      for (int r = 0; r < 16; ++r) acc[r] = 0.f;
#pragma unroll
      for (int s = 0; s < 8; ++s)
        acc = __builtin_amdgcn_mfma_f32_32x32x16_bf16(afr[i][s], bfr[tt][s], acc, 0, 0, 0);
      int ot = 2 * wv + i;
      int t = tt * 32 + l31;
      float sc = (ot < 4) ? 1.44269504f : 1.0f;  // scale q (o<128) by log2e
#pragma unroll
      for (int r = 0; r < 16; ++r) {
        int orow = (r & 3) + 8 * (r >> 2) + 4 * (lane >> 5);
        float v = acc[r] + cqk[ot * 32 + orow];
        v = v > 0.f ? v : 0.01f * v;
        obuf[t * 258 + ot * 32 + orow] = f2bf(v * sc);
      }
    }
  }
  __syncthreads();

  const u32* ob32 = (const u32*)obuf;
#pragma unroll
  for (int g = 0; g < 8; ++g) {
    int G = wv * 8 + g;
    int mat = G >> 4;
    int t = (G & 15) * 4 + (lane >> 4);
    int og2 = lane & 15;
    int wbase = t * 129 + mat * 64 + og2 * 4;
    u32x4 vv = {ob32[wbase], ob32[wbase + 1], ob32[wbase + 2], ob32[wbase + 3]};
    // frag-major dst: o-range [og2*8, og2*8+8) of row tg
    int tg = t0 + t;
    int kb = tg >> 5, tw = tg & 31;
    int s = og2 >> 1, hb = og2 & 1;
    u16* base = mat ? kT : qT;
    size_t off = (((size_t)b * 64 + kb) * 8 + s) * 512 + (hb * 32 + tw) * 8;
    *(u32x4*)(base + off) = vv;
  }
}

// ---------------------------------------------------------------------------
// attn v14 (resubmit; R9 was the same container-infra failure as R5,
// kernel re-audited clean): DS-pipe reduction.
// (1) frag-major qT/kT/vB -> every LDS read is a CONTIGUOUS 1KB wave read
//     (conflict-free) and staging is a flat 32KB copy;
// (2) global_load_lds width-16 staging: no staging VGPRs, no ds_writes;
// (3) fat waves: 8 waves = qg(2: 64 q) x kq(4: 32-k quarter of 128-k tile);
//     each kf/vf frag feeds 2 MFMAs -> K/V LDS reads halve.
// DS instrs/iter: 320 -> ~128. pacc[4][2]=128 VGPR; peak ~250 < 256 cap.
// Epilogue: one-time 4-way kq-partial combine via LDS rounds (dead dbuf).
#define KTILE 128
#define NKT  (T_ / KTILE)
#define PTSTR 136
#define CINIT 0.52876637f   // log2(log2 e)

__global__ __launch_bounds__(512, 2) void attn_mfma_kernel(
    const u16* __restrict__ qT, const u16* __restrict__ kT,
    const u16* __restrict__ vB, const u16* __restrict__ Ao_bf,
    const float* __restrict__ co, const float* __restrict__ Aofp,
    const float* __restrict__ meanv, float* __restrict__ out) {
  extern __shared__ u16 smem[];
  // dbuf: K [0,32768) u16, V [32768,65536) u16 (each: 2 bufs x 16384)
  u16* kb0 = smem;
  u16* kb1 = smem + 16384;
  u16* vb0 = smem + 32768;
  u16* vb1 = smem + 49152;
  float* dls = (float*)(smem + 65536);   // 512 f32, bytes [131072, 133120)
  float* pbuf = (float*)smem;            // epilogue: 32 slots x 4KB
  u16* ptbuf = smem + 32768;             // epilogue: [128][PTSTR] in dead p1

  int b = blockIdx.y;
  int q0 = blockIdx.x * 128;
  int tid = threadIdx.x;
  int lane = tid & 63;
  int wv = tid >> 6;                 // 0..7
  int l31 = lane & 31;
  int h = lane >> 5;
  int qg = wv & 1;                   // q-group: q-tiles {2qg, 2qg+1}
  int kq = wv >> 1;                  // 32-k quarter of the 128-k tile

  // persistent Q B-frags for both q-tiles (frag-major, coalesced)
  bf16x8 qfA[8], qfB[8];
  {
    const u16* qa = qT + (((size_t)b * 64 + (q0 >> 5) + 2 * qg) * 8) * 512 + lane * 8;
    const u16* qb = qa + 8 * 512;
#pragma unroll
    for (int s = 0; s < 8; ++s) {
      qfA[s] = ldfrag(qa + s * 512);
      qfB[s] = ldfrag(qb + s * 512);
    }
  }

  // stage tile 0 (32 chunks K + 32 V, 4+4 per wave, DMA)
  {
    const u16* gk = kT + ((size_t)(b * 64) * 8) * 512;
    const u16* gv = vB + ((size_t)(b * 64) * 8) * 512;
#pragma unroll
    for (int c2 = 0; c2 < 4; ++c2) {
      int ch = wv * 4 + c2;
      g2l16(gk + (size_t)ch * 512 + lane * 8, kb0 + ch * 512);
      g2l16(gv + (size_t)ch * 512 + lane * 8, vb0 + ch * 512);
    }
  }

  f32x16 pacc[4][2];
  float den0 = 0.f, den1 = 0.f;
#pragma unroll
  for (int mt = 0; mt < 4; ++mt)
#pragma unroll
    for (int i = 0; i < 16; ++i) { pacc[mt][0][i] = 0.f; pacc[mt][1][i] = 0.f; }

  __syncthreads();  // tile 0 staged (syncthreads drains vmcnt)

  for (int kt = 0; kt < NKT; ++kt) {
    u16* kcur = (kt & 1) ? kb1 : kb0;
    u16* vcur = (kt & 1) ? vb1 : vb0;

    // issue DMA staging of tile kt+1 (into the buffer freed at last barrier)
    if (kt + 1 < NKT) {
      const u16* gk = kT + ((size_t)(b * 64 + (kt + 1) * 4) * 8) * 512;
      const u16* gv = vB + ((size_t)(b * 64 + (kt + 1) * 4) * 8) * 512;
      u16* lk = (kt & 1) ? kb0 : kb1;
      u16* lv = (kt & 1) ? vb0 : vb1;
#pragma unroll
      for (int c2 = 0; c2 < 4; ++c2) {
        int ch = wv * 4 + c2;
        g2l16(gk + (size_t)ch * 512 + lane * 8, lk + ch * 512);
        g2l16(gv + (size_t)ch * 512 + lane * 8, lv + ch * 512);
      }
    }

    // S for both q-tiles; each kf load feeds 2 MFMAs
    f32x16 sa, sb;
#pragma unroll
    for (int i = 0; i < 16; ++i) { sa[i] = CINIT; sb[i] = CINIT; }
    {
      const u16* kl = kcur + (kq * 8) * 512 + lane * 8;
#pragma unroll
      for (int s = 0; s < 8; ++s) {
        bf16x8 kf = ldfrag(kl + s * 512);
        sa = __builtin_amdgcn_mfma_f32_32x32x16_bf16(kf, qfA[s], sa, 0, 0, 0);
        sb = __builtin_amdgcn_mfma_f32_32x32x16_bf16(kf, qfB[s], sb, 0, 0, 0);
      }
    }

    // diagonal adjust (scaled domain): x -> x*d + C*(1-d)
    int kglob = kt * KTILE + kq * 32;
    if (kglob == q0 + (2 * qg) * 32) {
#pragma unroll
      for (int r = 0; r < 16; ++r) {
        int row = (r & 3) + 8 * (r >> 2) + 4 * h;
        if (row == l31) sa[r] = fmaf(sa[r], 0.97790291f, 0.01168420f);
      }
    } else if (kglob == q0 + (2 * qg + 1) * 32) {
#pragma unroll
      for (int r = 0; r < 16; ++r) {
        int row = (r & 3) + 8 * (r >> 2) + 4 * h;
        if (row == l31) sb[r] = fmaf(sb[r], 0.97790291f, 0.01168420f);
      }
    }

    // softmax + pack + half-wave exchange, per q-tile
    bf16x8 bwA0, bwA1, bwB0, bwB1;
    {
      float w[16];
#pragma unroll
      for (int r = 0; r < 16; ++r) w[r] = ex2(ex2(sa[r]));
      float d0 = (w[0] + w[1]) + (w[2] + w[3]);
      float d1 = (w[4] + w[5]) + (w[6] + w[7]);
      float d2 = (w[8] + w[9]) + (w[10] + w[11]);
      float d3 = (w[12] + w[13]) + (w[14] + w[15]);
      den0 += (d0 + d1) + (d2 + d3);
      u32 p00 = pk2(w[0], w[1]),  p01 = pk2(w[2], w[3]);
      u32 p10 = pk2(w[4], w[5]),  p11 = pk2(w[6], w[7]);
      u32 p20 = pk2(w[8], w[9]),  p21 = pk2(w[10], w[11]);
      u32 p30 = pk2(w[12], w[13]), p31 = pk2(w[14], w[15]);
      u32 e0 = __shfl_xor(h ? p00 : p10, 32, 64);
      u32 e1 = __shfl_xor(h ? p01 : p11, 32, 64);
      u32 e2 = __shfl_xor(h ? p20 : p30, 32, 64);
      u32 e3 = __shfl_xor(h ? p21 : p31, 32, 64);
      u32x4 f0 = h ? u32x4{e0, e1, p10, p11} : u32x4{p00, p01, e0, e1};
      u32x4 f1 = h ? u32x4{e2, e3, p30, p31} : u32x4{p20, p21, e2, e3};
      bwA0 = __builtin_bit_cast(bf16x8, f0);
      bwA1 = __builtin_bit_cast(bf16x8, f1);
    }
    {
      float w[16];
#pragma unroll
      for (int r = 0; r < 16; ++r) w[r] = ex2(ex2(sb[r]));
      float d0 = (w[0] + w[1]) + (w[2] + w[3]);
      float d1 = (w[4] + w[5]) + (w[6] + w[7]);
      float d2 = (w[8] + w[9]) + (w[10] + w[11]);
      float d3 = (w[12] + w[13]) + (w[14] + w[15]);
      den1 += (d0 + d1) + (d2 + d3);
      u32 p00 = pk2(w[0], w[1]),  p01 = pk2(w[2], w[3]);
      u32 p10 = pk2(w[4], w[5]),  p11 = pk2(w[6], w[7]);
      u32 p20 = pk2(w[8], w[9]),  p21 = pk2(w[10], w[11]);
      u32 p30 = pk2(w[12], w[13]), p31 = pk2(w[14], w[15]);
      u32 e0 = __shfl_xor(h ? p00 : p10, 32, 64);
      u32 e1 = __shfl_xor(h ? p01 : p11, 32, 64);
      u32 e2 = __shfl_xor(h ? p20 : p30, 32, 64);
      u32 e3 = __shfl_xor(h ? p21 : p31, 32, 64);
      u32x4 f0 = h ? u32x4{e0, e1, p10, p11} : u32x4{p00, p01, e0, e1};
      u32x4 f1 = h ? u32x4{e2, e3, p30, p31} : u32x4{p20, p21, e2, e3};
      bwB0 = __builtin_bit_cast(bf16x8, f0);
      bwB1 = __builtin_bit_cast(bf16x8, f1);
    }

    // PV: each vf load feeds both q-tiles
#pragma unroll
    for (int mt = 0; mt < 4; ++mt) {
      const u16* vl = vcur + ((kq * 4 + mt) * 2) * 512 + lane * 8;
      bf16x8 vf0 = ldfrag(vl);
      bf16x8 vf1 = ldfrag(vl + 512);
      pacc[mt][0] = __builtin_amdgcn_mfma_f32_32x32x16_bf16(vf0, bwA0, pacc[mt][0], 0, 0, 0);
      pacc[mt][0] = __builtin_amdgcn_mfma_f32_32x32x16_bf16(vf1, bwA1, pacc[mt][0], 0, 0, 0);
      pacc[mt][1] = __builtin_amdgcn_mfma_f32_32x32x16_bf16(vf0, bwB0, pacc[mt][1], 0, 0, 0);
      pacc[mt][1] = __builtin_amdgcn_mfma_f32_32x32x16_bf16(vf1, bwB1, pacc[mt][1], 0, 0, 0);
    }

    __syncthreads();  // tile kt reads done + tile kt+1 DMA drained
  }

  // ---- epilogue: 4-way kq-partial combine ----
  float dqA = den0 + __shfl_xor(den0, 32, 64);
  float dqB = den1 + __shfl_xor(den1, 32, 64);
  if (lane < 32) {
    dls[(kq * 4 + 2 * qg + 0) * 32 + l31] = dqA;
    dls[(kq * 4 + 2 * qg + 1) * 32 + l31] = dqB;
  }
  __syncthreads();  // [E0] dbuf dead, dls visible

  // round A: kq 1 -> p0 slots, kq 3 -> p1 slots
  if (kq & 1) {
    int p = (kq == 3) ? 16 : 0;
#pragma unroll
    for (int mt = 0; mt < 4; ++mt)
#pragma unroll
      for (int cc = 0; cc < 2; ++cc) {
        float* pb = &pbuf[(size_t)(p + (qg * 2 + cc) * 4 + mt) * 1024 + lane * 16];
#pragma unroll
        for (int g = 0; g < 4; ++g) {
          f32x4 v = {pacc[mt][cc][4 * g], pacc[mt][cc][4 * g + 1],
                     pacc[mt][cc][4 * g + 2], pacc[mt][cc][4 * g + 3]};
          *(f32x4*)(pb + 4 * g) = v;
        }
      }
  }
  __syncthreads();  // [E1]

  if (!(kq & 1)) {  // kq0 absorbs p0, kq2 absorbs p1
    int p = (kq == 2) ? 16 : 0;
#pragma unroll
    for (int mt = 0; mt < 4; ++mt)
#pragma unroll
      for (int cc = 0; cc < 2; ++cc) {
        const float* pb = &pbuf[(size_t)(p + (qg * 2 + cc) * 4 + mt) * 1024 + lane * 16];
#pragma unroll
        for (int g = 0; g < 4; ++g) {
          f32x4 t = *(const f32x4*)(pb + 4 * g);
          pacc[mt][cc][4 * g]     += t[0];
          pacc[mt][cc][4 * g + 1] += t[1];
          pacc[mt][cc][4 * g + 2] += t[2];
          pacc[mt][cc][4 * g + 3] += t[3];
        }
      }
  }
  __syncthreads();  // [E2]

  // round B: kq2 publishes its (2+3) sum into p0 slots
  if (kq == 2) {
#pragma unroll
    for (int mt = 0; mt < 4; ++mt)
#pragma unroll
      for (int cc = 0; cc < 2; ++cc) {
        float* pb = &pbuf[(size_t)((qg * 2 + cc) * 4 + mt) * 1024 + lane * 16];
#pragma unroll
        for (int g = 0; g < 4; ++g) {
          f32x4 v = {pacc[mt][cc][4 * g], pacc[mt][cc][4 * g + 1],
                     pacc[mt][cc][4 * g + 2], pacc[mt][cc][4 * g + 3]};
          *(f32x4*)(pb + 4 * g) = v;
        }
      }
  }
  __syncthreads();  // [E3]

  if (kq == 0) {  // final sum, normalize, write attn^T (q-major) to ptbuf
#pragma unroll
    for (int cc = 0; cc < 2; ++cc) {
      int qt = 2 * qg + cc;
      float rden = 1.f / (dls[(0 * 4 + qt) * 32 + l31] + dls[(1 * 4 + qt) * 32 + l31]
                        + dls[(2 * 4 + qt) * 32 + l31] + dls[(3 * 4 + qt) * 32 + l31]);
#pragma unroll
      for (int mt = 0; mt < 4; ++mt) {
        const float* pb = &pbuf[(size_t)((qg * 2 + cc) * 4 + mt) * 1024 + lane * 16];
#pragma unroll
        for (int g = 0; g < 4; ++g) {
          f32x4 t = *(const f32x4*)(pb + 4 * g);
          float v0 = (pacc[mt][cc][4 * g + 0] + t[0]) * rden;
          float v1 = (pacc[mt][cc][4 * g + 1] + t[1]) * rden;
          float v2 = (pacc[mt][cc][4 * g + 2] + t[2]) * rden;
          float v3 = (pacc[mt][cc][4 * g + 3] + t[3]) * rden;
          int m0 = mt * 32 + 8 * g + 4 * h;
          u32x2 wp = {pk2(v0, v1), pk2(v2, v3)};
          *(u32x2*)&ptbuf[(qt * 32 + l31) * PTSTR + m0] = wp;
        }
      }
    }
  }
  __syncthreads();  // [E4] attn^T visible

  // o-MLP epilogue: 8 waves = o-tile (wv&3) x q-pair (wv>>2), 16 MFMA each
  int lh8 = h * 8;
  bf16x8 aofr[8];
  {
    const u16* ap = Ao_bf + ((wv & 3) * 32 + l31) * 128 + lh8;
#pragma unroll
    for (int s = 0; s < 8; ++s) aofr[s] = ldfrag(ap + 16 * s);
  }
#pragma unroll
  for (int j = 0; j < 2; ++j) {
    int qt2 = (wv >> 2) * 2 + j;
    bf16x8 pfr[8];
    const u16* pp = &ptbuf[(qt2 * 32 + l31) * PTSTR + lh8];
#pragma unroll
    for (int s = 0; s < 8; ++s) pfr[s] = ldfrag(pp + 16 * s);
    f32x16 oacc;
#pragma unroll
    for (int r = 0; r < 16; ++r) oacc[r] = 0.f;
#pragma unroll
    for (int s = 0; s < 8; ++s)
      oacc = __builtin_amdgcn_mfma_f32_32x32x16_bf16(aofr[s], pfr[s], oacc, 0, 0, 0);
#pragma unroll
    for (int r = 0; r < 16; ++r) {
      int orow = (wv & 3) * 32 + (r & 3) + 8 * (r >> 2) + 4 * h;
      float v = oacc[r] + co[orow];
      v = v > 0.f ? v : 0.01f * v;
      out[((size_t)(b * M_ + orow)) * TOUT_ + q0 + qt2 * 32 + l31] = v;
    }
  }

  // rep_ex tail
  if (blockIdx.x == 0 && tid < 128) {
    float acc = co[tid];
    const float* mv = meanv + b * 128;
    for (int m = 0; m < 128; ++m) acc = fmaf(Aofp[tid * 128 + m], mv[m], acc);
    acc = acc > 0.f ? acc : 0.01f * acc;
    out[((size_t)(b * M_ + tid)) * TOUT_ + 2048] = acc;
  }
}

// ---------------------------------------------------------------------------
extern "C" void kernel_launch(void* const* d_in, const int* in_sizes, int n_in,
                              void* d_out, int out_size, void* d_ws, size_t ws_size,
                              hipStream_t stream) {
  (void)in_sizes; (void)n_in; (void)out_size; (void)ws_size;
  const float* pattern = (const float*)d_in[0];
  const float* value   = (const float*)d_in[1];
  const float* Wq1 = (const float*)d_in[3];
  const float* bq1 = (const float*)d_in[4];
  const float* Wq2 = (const float*)d_in[5];
  const float* bq2 = (const float*)d_in[6];
  const float* Wk1 = (const float*)d_in[7];
  const float* bk1 = (const float*)d_in[8];
  const float* Wk2 = (const float*)d_in[9];
  const float* bk2 = (const float*)d_in[10];
  const float* Wo1 = (const float*)d_in[11];
  const float* bo1 = (const float*)d_in[12];
  const float* Wo2 = (const float*)d_in[13];
  const float* bo2 = (const float*)d_in[14];

  float* ws     = (float*)d_ws;
  float* A      = ws + A_OFF;
  float* c      = ws + C_OFF;
  float* meanv  = ws + MEAN_OFF;
  u16*   Aqk_bf = (u16*)(ws + AQKBF_OFF);
  u16*   Ao_bf  = (u16*)(ws + AOBF_OFF);
  u16*   qT     = (u16*)(ws + QT_OFF);
  u16*   kT     = (u16*)(ws + KT_OFF);
  u16*   vB     = (u16*)(ws + VB_OFF);
  float* out    = (float*)d_out;

  fuse_weights_all<<<384 + B_ * M_, 128, 0, stream>>>(
      Wq1, bq1, Wq2, bq2, Wk1, bk1, Wk2, bk2, Wo1, bo1, Wo2, bo2,
      A, c, Aqk_bf, Ao_bf, value, vB, meanv);

  prep_kernel<<<512, 256, 0, stream>>>(pattern, Aqk_bf, c, qT, kT);

  // LDS: K/V dbuf 131072 B + dls 2048 B = 133120 B -> 1 block/CU
  size_t lds_bytes = 133120;
  attn_mfma_kernel<<<dim3(T_ / 128, B_), 512, lds_bytes, stream>>>(
      qT, kT, vB, Ao_bf, c + 256, A, meanv, out);
}

// Round 11
// 188.901 us; speedup vs baseline: 1.0838x; 1.0838x over previous
//
#include <hip/hip_runtime.h>
#include <hip/hip_bf16.h>
#include <math.h>

#define B_    16
#define M_    128
#define T_    2048
#define H_    512
#define TOUT_ 2049

typedef unsigned short u16;
typedef unsigned int   u32;
typedef __bf16 bf16x8 __attribute__((ext_vector_type(8)));
typedef float  f32x16 __attribute__((ext_vector_type(16)));
typedef float  f32x4  __attribute__((ext_vector_type(4)));
typedef u32    u32x4  __attribute__((ext_vector_type(4)));
typedef u32    u32x2  __attribute__((ext_vector_type(2)));

// ws layout (float units):
#define A_OFF     0                       // fp32 Ao only [128][128]
#define C_OFF     16384                   // c[3][128]
#define MEAN_OFF  16896                   // meanv [2048]
#define AQKBF_OFF 19200                   // u16 [256][128] = 16384 fl
#define AOBF_OFF  35584                   // u16 [128][128] = 8192 fl
#define QT_OFF    43776
#define KT_OFF    (43776 + 2097152)
#define VB_OFF    (43776 + 2 * 2097152)

static __device__ __forceinline__ u16 f2bf(float f) {
  u32 u = __float_as_uint(f);
  u = (u + 0x7FFFu + ((u >> 16) & 1u)) >> 16;
  return (u16)u;
}
static __device__ __forceinline__ u32 pk2(float lo, float hi) {
  __hip_bfloat162 h = __float22bfloat162_rn(float2{lo, hi});
  u32 r;
  __builtin_memcpy(&r, &h, 4);
  return r;
}
static __device__ __forceinline__ bf16x8 ldfrag(const u16* p) {
  return __builtin_bit_cast(bf16x8, *(const u32x4*)p);
}
static __device__ __forceinline__ float ex2(float x) {
#if __has_builtin(__builtin_amdgcn_exp2f)
  return __builtin_amdgcn_exp2f(x);  // v_exp_f32 = 2^x
#else
  return exp2f(x);
#endif
}

// ---------------------------------------------------------------------------
// fuse: blocks [0,384) = weight fusion; blocks [384,896) = value cast +
// windowed mean, ONE WAVE PER 2 ROWS, shuffle-reduce only (no barriers).
__global__ __launch_bounds__(128) void fuse_weights_all(
    const float* __restrict__ W1q, const float* __restrict__ b1q,
    const float* __restrict__ W2q, const float* __restrict__ b2q,
    const float* __restrict__ W1k, const float* __restrict__ b1k,
    const float* __restrict__ W2k, const float* __restrict__ b2k,
    const float* __restrict__ W1o, const float* __restrict__ b1o,
    const float* __restrict__ W2o, const float* __restrict__ b2o,
    float* __restrict__ A, float* __restrict__ c,
    u16* __restrict__ Aqk_bf, u16* __restrict__ Ao_bf,
    const float* __restrict__ value, u16* __restrict__ vb,
    float* __restrict__ meanv) {
  __shared__ float w2row[H_];
  int tid = threadIdx.x;

  if (blockIdx.x >= 384) {
    int bm0 = (blockIdx.x - 384) * 4;
    int w = tid >> 6, lane = tid & 63;
#pragma unroll
    for (int rr = 0; rr < 2; ++rr) {
      int bm = bm0 + w * 2 + rr;
      const float* row = value + (size_t)bm * T_;
      u16* vrow = vb + (size_t)bm * T_;
      float s = 0.f;
#pragma unroll
      for (int seg = 0; seg < 8; ++seg) {
        int col = seg * 256 + lane * 4;
        float4 a = *(const float4*)(row + col);
        u32x2 o = {pk2(a.x, a.y), pk2(a.z, a.w)};
        *(u32x2*)&vrow[col] = o;
        if (col >= 33 && col < T_ - 4) {
          s += ((a.x + a.y) + (a.z + a.w));
        } else {
          if (col + 0 >= 33 && col + 0 < T_ - 1) s += a.x;
          if (col + 1 >= 33 && col + 1 < T_ - 1) s += a.y;
          if (col + 2 >= 33 && col + 2 < T_ - 1) s += a.z;
          if (col + 3 >= 33 && col + 3 < T_ - 1) s += a.w;
        }
      }
#pragma unroll
      for (int off = 32; off > 0; off >>= 1) s += __shfl_down(s, off, 64);
      if (lane == 0) meanv[bm] = s * (1.f / 2014.f);
    }
    return;
  }

  int which = blockIdx.x >> 7;
  int o = blockIdx.x & 127;
  const float* W1 = which == 0 ? W1q : which == 1 ? W1k : W1o;
  const float* b1 = which == 0 ? b1q : which == 1 ? b1k : b1o;
  const float* W2 = which == 0 ? W2q : which == 1 ? W2k : W2o;
  const float* b2 = which == 0 ? b2q : which == 1 ? b2k : b2o;
  int m = tid;
  for (int h = m; h < H_; h += 128) w2row[h] = W2[o * H_ + h];
  __syncthreads();
  float acc = 0.f;
#pragma unroll 8
  for (int h = 0; h < H_; ++h) acc = fmaf(w2row[h], W1[h * M_ + m], acc);
  u16 ab = f2bf(acc);
  if (which == 0)      Aqk_bf[o * 128 + m] = ab;
  else if (which == 1) Aqk_bf[(128 + o) * 128 + m] = ab;
  else               { Ao_bf[o * 128 + m] = ab; A[o * M_ + m] = acc; }
  if (m < 64) {
    float cc = 0.f;
    for (int h = m; h < H_; h += 64) cc = fmaf(w2row[h], b1[h], cc);
#pragma unroll
    for (int off = 32; off > 0; off >>= 1) cc += __shfl_down(cc, off, 64);
    if (m == 0) c[which * 128 + o] = cc + b2[o];
  }
}

// ---------------------------------------------------------------------------
// prep v2: width-32 t-tiles, 1024 blocks (4/CU, was 2/CU at width 64).
// Halves per-thread transpose ds_reads (128->64) and obuf traffic; stores
// obuf as packed u32 (was scalar u16). Output layout unchanged (row-major
// qT/kT, q pre-scaled by log2e).
#define XS2 36

__global__ __launch_bounds__(256) void prep_kernel(
    const float* __restrict__ pattern, const u16* __restrict__ Aqk_bf,
    const float* __restrict__ cqk, u16* __restrict__ qT, u16* __restrict__ kT) {
  __shared__ alignas(16) float xsf[128 * XS2];  // 18432 B
  int bx = blockIdx.x;
  int tid = threadIdx.x;

  int b = bx >> 6;
  int t0 = (bx & 63) * 32;
  int lane = tid & 63;
  int wv = tid >> 6;
  int l31 = lane & 31;
  int h = lane >> 5;
  int lh8 = h * 8;

  bf16x8 afr[2][8];
#pragma unroll
  for (int i = 0; i < 2; ++i) {
    const u16* ap = Aqk_bf + ((2 * wv + i) * 32 + l31) * 128 + lh8;
#pragma unroll
    for (int s = 0; s < 8; ++s) afr[i][s] = ldfrag(ap + 16 * s);
  }

  // stage pattern [128 m][32 t]
  {
    int m = tid >> 1;
    int cb = (tid & 1) * 16;
#pragma unroll
    for (int j = 0; j < 4; ++j) {
      float4 v = *(const float4*)&pattern[(size_t)(b * M_ + m) * T_ + t0 + cb + j * 4];
      *(float4*)&xsf[m * XS2 + cb + j * 4] = v;
    }
  }
  __syncthreads();

  bf16x8 bfr[8];
#pragma unroll
  for (int s = 0; s < 8; ++s) {
    float v0 = xsf[(s * 16 + lh8 + 0) * XS2 + l31];
    float v1 = xsf[(s * 16 + lh8 + 1) * XS2 + l31];
    float v2 = xsf[(s * 16 + lh8 + 2) * XS2 + l31];
    float v3 = xsf[(s * 16 + lh8 + 3) * XS2 + l31];
    float v4 = xsf[(s * 16 + lh8 + 4) * XS2 + l31];
    float v5 = xsf[(s * 16 + lh8 + 5) * XS2 + l31];
    float v6 = xsf[(s * 16 + lh8 + 6) * XS2 + l31];
    float v7 = xsf[(s * 16 + lh8 + 7) * XS2 + l31];
    u32x4 p = {pk2(v0, v1), pk2(v2, v3), pk2(v4, v5), pk2(v6, v7)};
    bfr[s] = __builtin_bit_cast(bf16x8, p);
  }
  __syncthreads();  // xsf dead -> obuf

  u16* obuf = (u16*)xsf;  // [32 t][258 o] u16 = 16512 B
  u32* ob32w = (u32*)xsf;
#pragma unroll
  for (int i = 0; i < 2; ++i) {
    f32x16 acc;
#pragma unroll
    for (int r = 0; r < 16; ++r) acc[r] = 0.f;
#pragma unroll
    for (int s = 0; s < 8; ++s)
      acc = __builtin_amdgcn_mfma_f32_32x32x16_bf16(afr[i][s], bfr[s], acc, 0, 0, 0);
    int ot = 2 * wv + i;
    int t = l31;
    float sc = (ot < 4) ? 1.44269504f : 1.0f;  // scale q (o<128) by log2e
#pragma unroll
    for (int g = 0; g < 4; ++g) {
      int orow0 = 8 * g + 4 * h;
      float q0 = acc[4 * g + 0] + cqk[ot * 32 + orow0 + 0];
      float q1 = acc[4 * g + 1] + cqk[ot * 32 + orow0 + 1];
      float q2 = acc[4 * g + 2] + cqk[ot * 32 + orow0 + 2];
      float q3 = acc[4 * g + 3] + cqk[ot * 32 + orow0 + 3];
      q0 = (q0 > 0.f ? q0 : 0.01f * q0) * sc;
      q1 = (q1 > 0.f ? q1 : 0.01f * q1) * sc;
      q2 = (q2 > 0.f ? q2 : 0.01f * q2) * sc;
      q3 = (q3 > 0.f ? q3 : 0.01f * q3) * sc;
      int u16i = t * 258 + ot * 32 + orow0;  // even
      ob32w[(u16i >> 1) + 0] = pk2(q0, q1);
      ob32w[(u16i >> 1) + 1] = pk2(q2, q3);
    }
  }
  __syncthreads();

  const u32* ob32 = (const u32*)obuf;
  {
    int t = tid >> 3;
#pragma unroll
    for (int j = 0; j < 4; ++j) {
      int qd = (tid & 7) * 4 + j;      // u32-quad index 0..31 (128 u32/row)
      int base = t * 129 + qd * 4;
      u32x4 vv = {ob32[base], ob32[base + 1], ob32[base + 2], ob32[base + 3]};
      int mat = qd >> 4;
      u32* dst = (u32*)((mat ? kT : qT) + ((size_t)(b * T_ + t0 + t)) * 128)
               + (qd & 15) * 4;
      *(u32x4*)dst = vv;
    }
  }
}

// ---------------------------------------------------------------------------
// attn v8 (REVERT to best-known: 61.0 us measured R2). 128-q blocks, 512
// thr, 1 block/CU; 128-k tiles (NKT=16), Q frags from global, exp2-
// prescaled double-exp, setprio around MFMA clusters.
// Waves: qt = wv&3 (32 q's), kh = wv>>2 (64-k half of the 128-k tile).
#define QSTR 136  // u16: 68 words == 4 mod 32 (conflict-free)
#define VSTR 136
#define KTILE 128
#define NKT  (T_ / KTILE)
#define CINIT 0.52876637f   // log2(log2 e)

__global__ __launch_bounds__(512, 2) void attn_mfma_kernel(
    const u16* __restrict__ qT, const u16* __restrict__ kT,
    const u16* __restrict__ vB, const u16* __restrict__ Ao_bf,
    const float* __restrict__ co, const float* __restrict__ Aofp,
    const float* __restrict__ meanv, float* __restrict__ out) {
  extern __shared__ u16 smem[];
  u16* ks0 = smem;                        // [128][QSTR] x2 (dbuf)
  u16* ks1 = ks0 + 128 * QSTR;
  u16* vs0 = ks1 + 128 * QSTR;            // [128][VSTR] x2 (dbuf)
  u16* vs1 = vs0 + 128 * VSTR;
  float* dls  = (float*)(vs1 + 128 * VSTR);  // [128]
  float* pbuf = (float*)ks0;              // 64 KB epilogue alias (ks dead)
  u16*   ptbuf = vs0;                     // [128][QSTR] epilogue alias (vs dead)

  int b = blockIdx.y;
  int q0 = blockIdx.x * 128;
  int tid = threadIdx.x;
  int lane = tid & 63;
  int wv = tid >> 6;                 // 0..7
  int l31 = lane & 31;
  int h = lane >> 5;
  int lh8 = h * 8;
  int qt = wv & 3;                   // q-tile (32 q's)
  int kh = wv >> 2;                  // 64-k half of 128-k tile

  const u16* gkb = kT + (size_t)b * T_ * 128;
  const u16* gvb = vB + (size_t)b * M_ * T_;
  int kr = tid >> 4, kc = (tid & 15) * 8;   // 32 rows/iter, 4 iters

  // persistent Q B-frags straight from global (one-time, L2-resident)
  bf16x8 qfrag[8];
  {
    const u16* qrow = qT + (size_t)(b * T_ + q0 + qt * 32 + l31) * 128 + lh8;
#pragma unroll
    for (int s = 0; s < 8; ++s) qfrag[s] = ldfrag(qrow + s * 16);
  }

  u32x4 kreg[4], vreg[4];
#pragma unroll
  for (int it = 0; it < 4; ++it) {
    kreg[it] = *(const u32x4*)&gkb[(size_t)(it * 32 + kr) * 128 + kc];
    vreg[it] = *(const u32x4*)&gvb[(size_t)(it * 32 + kr) * T_ + kc];
  }
  // write tile 0, load tile 1
#pragma unroll
  for (int it = 0; it < 4; ++it) {
    *(u32x4*)&ks0[(it * 32 + kr) * QSTR + kc] = kreg[it];
    *(u32x4*)&vs0[(it * 32 + kr) * VSTR + kc] = vreg[it];
  }
#pragma unroll
  for (int it = 0; it < 4; ++it) {
    kreg[it] = *(const u32x4*)&gkb[(size_t)(KTILE + it * 32 + kr) * 128 + kc];
    vreg[it] = *(const u32x4*)&gvb[(size_t)(it * 32 + kr) * T_ + KTILE + kc];
  }

  f32x16 pacc[4];
  float den = 0.f;
#pragma unroll
  for (int i = 0; i < 16; ++i) {
    pacc[0][i] = 0.f; pacc[1][i] = 0.f; pacc[2][i] = 0.f; pacc[3][i] = 0.f;
  }

  for (int kt = 0; kt < NKT; ++kt) {
    int k0 = kt * KTILE;
    u16* kcur = (kt & 1) ? ks1 : ks0;
    u16* knxt = (kt & 1) ? ks0 : ks1;
    u16* vcur = (kt & 1) ? vs1 : vs0;
    u16* vnxt = (kt & 1) ? vs0 : vs1;
    __syncthreads();  // [T] tile-kt staging visible; prev readers drained

    // S'[k][q] = mfma(K, Q) over this wave's 64 k's (2 x 32-row subtiles)
    f32x16 sacc_a, sacc_b;
#pragma unroll
    for (int i = 0; i < 16; ++i) { sacc_a[i] = CINIT; sacc_b[i] = CINIT; }
    {
      const u16* krowa = &kcur[(kh * 64 + l31) * QSTR + lh8];
      const u16* krowb = krowa + 32 * QSTR;
      __builtin_amdgcn_s_setprio(1);
#pragma unroll
      for (int s = 0; s < 8; ++s) {
        bf16x8 kfa = ldfrag(krowa + s * 16);
        sacc_a = __builtin_amdgcn_mfma_f32_32x32x16_bf16(kfa, qfrag[s], sacc_a, 0, 0, 0);
      }
#pragma unroll
      for (int s = 0; s < 8; ++s) {
        bf16x8 kfb = ldfrag(krowb + s * 16);
        sacc_b = __builtin_amdgcn_mfma_f32_32x32x16_bf16(kfb, qfrag[s], sacc_b, 0, 0, 0);
      }
      __builtin_amdgcn_s_setprio(0);
    }

    // stage tile kt+1 into nxt buffers; prefetch tile kt+2
    if (kt < NKT - 1) {
#pragma unroll
      for (int it = 0; it < 4; ++it) {
        *(u32x4*)&knxt[(it * 32 + kr) * QSTR + kc] = kreg[it];
        *(u32x4*)&vnxt[(it * 32 + kr) * VSTR + kc] = vreg[it];
      }
      int kn = (kt + 2 < NKT) ? (kt + 2) * KTILE : (NKT - 1) * KTILE;
#pragma unroll
      for (int it = 0; it < 4; ++it) {
        kreg[it] = *(const u32x4*)&gkb[(size_t)(kn + it * 32 + kr) * 128 + kc];
        vreg[it] = *(const u32x4*)&gvb[(size_t)(it * 32 + kr) * T_ + kn + kc];
      }
    }

    // diagonal adjust (scaled domain): x -> x*d + C*(1-d)
    if (k0 + kh * 64 == q0 + qt * 32) {
#pragma unroll
      for (int r = 0; r < 16; ++r) {
        int row = (r & 3) + 8 * (r >> 2) + 4 * h;
        if (row == l31) sacc_a[r] = fmaf(sacc_a[r], 0.97790291f, 0.01168420f);
      }
    } else if (k0 + kh * 64 + 32 == q0 + qt * 32) {
#pragma unroll
      for (int r = 0; r < 16; ++r) {
        int row = (r & 3) + 8 * (r >> 2) + 4 * h;
        if (row == l31) sacc_b[r] = fmaf(sacc_b[r], 0.97790291f, 0.01168420f);
      }
    }

    // ---- half A: w = exp2(exp2(s)), pack, exchange, PV slices 0,1 ----
    {
      float w[16];
#pragma unroll
      for (int r = 0; r < 16; ++r) w[r] = ex2(ex2(sacc_a[r]));
      float d0 = (w[0] + w[1]) + (w[2] + w[3]);
      float d1 = (w[4] + w[5]) + (w[6] + w[7]);
      float d2 = (w[8] + w[9]) + (w[10] + w[11]);
      float d3 = (w[12] + w[13]) + (w[14] + w[15]);
      den += (d0 + d1) + (d2 + d3);
      u32 p00 = pk2(w[0], w[1]),  p01 = pk2(w[2], w[3]);
      u32 p10 = pk2(w[4], w[5]),  p11 = pk2(w[6], w[7]);
      u32 p20 = pk2(w[8], w[9]),  p21 = pk2(w[10], w[11]);
      u32 p30 = pk2(w[12], w[13]), p31 = pk2(w[14], w[15]);
      u32 e0 = __shfl_xor(h ? p00 : p10, 32, 64);
      u32 e1 = __shfl_xor(h ? p01 : p11, 32, 64);
      u32 e2 = __shfl_xor(h ? p20 : p30, 32, 64);
      u32 e3 = __shfl_xor(h ? p21 : p31, 32, 64);
      u32x4 f0 = h ? u32x4{e0, e1, p10, p11} : u32x4{p00, p01, e0, e1};
      u32x4 f1 = h ? u32x4{e2, e3, p30, p31} : u32x4{p20, p21, e2, e3};
      bf16x8 bw0 = __builtin_bit_cast(bf16x8, f0);
      bf16x8 bw1 = __builtin_bit_cast(bf16x8, f1);
      __builtin_amdgcn_s_setprio(1);
#pragma unroll
      for (int mt = 0; mt < 4; ++mt) {
        const u16* vrow = &vcur[(mt * 32 + l31) * VSTR + kh * 64 + lh8];
        bf16x8 vf0 = ldfrag(vrow);
        bf16x8 vf1 = ldfrag(vrow + 16);
        pacc[mt] = __builtin_amdgcn_mfma_f32_32x32x16_bf16(vf0, bw0, pacc[mt], 0, 0, 0);
        pacc[mt] = __builtin_amdgcn_mfma_f32_32x32x16_bf16(vf1, bw1, pacc[mt], 0, 0, 0);
      }
      __builtin_amdgcn_s_setprio(0);
    }
    // ---- half B: slices 2,3 ----
    {
      float w[16];
#pragma unroll
      for (int r = 0; r < 16; ++r) w[r] = ex2(ex2(sacc_b[r]));
      float d0 = (w[0] + w[1]) + (w[2] + w[3]);
      float d1 = (w[4] + w[5]) + (w[6] + w[7]);
      float d2 = (w[8] + w[9]) + (w[10] + w[11]);
      float d3 = (w[12] + w[13]) + (w[14] + w[15]);
      den += (d0 + d1) + (d2 + d3);
      u32 p00 = pk2(w[0], w[1]),  p01 = pk2(w[2], w[3]);
      u32 p10 = pk2(w[4], w[5]),  p11 = pk2(w[6], w[7]);
      u32 p20 = pk2(w[8], w[9]),  p21 = pk2(w[10], w[11]);
      u32 p30 = pk2(w[12], w[13]), p31 = pk2(w[14], w[15]);
      u32 e0 = __shfl_xor(h ? p00 : p10, 32, 64);
      u32 e1 = __shfl_xor(h ? p01 : p11, 32, 64);
      u32 e2 = __shfl_xor(h ? p20 : p30, 32, 64);
      u32 e3 = __shfl_xor(h ? p21 : p31, 32, 64);
      u32x4 f0 = h ? u32x4{e0, e1, p10, p11} : u32x4{p00, p01, e0, e1};
      u32x4 f1 = h ? u32x4{e2, e3, p30, p31} : u32x4{p20, p21, e2, e3};
      bf16x8 bw2 = __builtin_bit_cast(bf16x8, f0);
      bf16x8 bw3 = __builtin_bit_cast(bf16x8, f1);
      __builtin_amdgcn_s_setprio(1);
#pragma unroll
      for (int mt = 0; mt < 4; ++mt) {
        const u16* vrow = &vcur[(mt * 32 + l31) * VSTR + kh * 64 + 32 + lh8];
        bf16x8 vf2 = ldfrag(vrow);
        bf16x8 vf3 = ldfrag(vrow + 16);
        pacc[mt] = __builtin_amdgcn_mfma_f32_32x32x16_bf16(vf2, bw2, pacc[mt], 0, 0, 0);
        pacc[mt] = __builtin_amdgcn_mfma_f32_32x32x16_bf16(vf3, bw3, pacc[mt], 0, 0, 0);
      }
      __builtin_amdgcn_s_setprio(0);
    }
  }

  // per-q denominator for this k-half (lane q = l31, both h halves summed)
  float dq = den + __shfl_xor(den, 32, 64);

  __syncthreads();  // [E1] all PV reads of ks/vs done -> aliases safe

  if (kh == 1) {
#pragma unroll
    for (int mt = 0; mt < 4; ++mt) {
      float* pb = &pbuf[((size_t)(qt * 4 + mt) * 64 + lane) * 16];
#pragma unroll
      for (int g = 0; g < 4; ++g) {
        f32x4 v = {pacc[mt][4 * g], pacc[mt][4 * g + 1],
                   pacc[mt][4 * g + 2], pacc[mt][4 * g + 3]};
        *(f32x4*)(pb + 4 * g) = v;
      }
    }
    if (lane < 32) dls[qt * 32 + lane] = dq;
  }
  __syncthreads();  // [E2]

  if (kh == 0) {
    float rden = 1.f / (dq + dls[qt * 32 + l31]);
#pragma unroll
    for (int mt = 0; mt < 4; ++mt) {
      const float* pb = &pbuf[((size_t)(qt * 4 + mt) * 64 + lane) * 16];
#pragma unroll
      for (int g = 0; g < 4; ++g) {
        f32x4 t = *(const f32x4*)(pb + 4 * g);
        float v0 = (pacc[mt][4 * g + 0] + t[0]) * rden;
        float v1 = (pacc[mt][4 * g + 1] + t[1]) * rden;
        float v2 = (pacc[mt][4 * g + 2] + t[2]) * rden;
        float v3 = (pacc[mt][4 * g + 3] + t[3]) * rden;
        int m0 = mt * 32 + 8 * g + 4 * h;
        u32x2 wp = {pk2(v0, v1), pk2(v2, v3)};
        *(u32x2*)&ptbuf[(qt * 32 + l31) * QSTR + m0] = wp;
      }
    }
  }
  __syncthreads();  // [E3] P^T visible

  // o-MLP epilogue: wave wv -> o-tile (wv&3), q-tiles {2*kh, 2*kh+1}
  bf16x8 aofr[8];
  {
    const u16* ap = Ao_bf + ((wv & 3) * 32 + l31) * 128 + lh8;
#pragma unroll
    for (int s = 0; s < 8; ++s) aofr[s] = ldfrag(ap + 16 * s);
  }
#pragma unroll
  for (int j = 0; j < 2; ++j) {
    int qt2 = kh * 2 + j;
    bf16x8 pfr[8];
    const u16* pp = &ptbuf[(qt2 * 32 + l31) * QSTR + lh8];
#pragma unroll
    for (int s = 0; s < 8; ++s) pfr[s] = ldfrag(pp + 16 * s);
    f32x16 oacc;
#pragma unroll
    for (int r = 0; r < 16; ++r) oacc[r] = 0.f;
#pragma unroll
    for (int s = 0; s < 8; ++s)
      oacc = __builtin_amdgcn_mfma_f32_32x32x16_bf16(aofr[s], pfr[s], oacc, 0, 0, 0);
#pragma unroll
    for (int r = 0; r < 16; ++r) {
      int orow = (wv & 3) * 32 + (r & 3) + 8 * (r >> 2) + 4 * h;
      float v = oacc[r] + co[orow];
      v = v > 0.f ? v : 0.01f * v;
      out[((size_t)(b * M_ + orow)) * TOUT_ + q0 + qt2 * 32 + l31] = v;
    }
  }

  // rep_ex tail
  if (blockIdx.x == 0 && tid < 128) {
    float acc = co[tid];
    const float* mv = meanv + b * 128;
    for (int m = 0; m < 128; ++m) acc = fmaf(Aofp[tid * 128 + m], mv[m], acc);
    acc = acc > 0.f ? acc : 0.01f * acc;
    out[((size_t)(b * M_ + tid)) * TOUT_ + 2048] = acc;
  }
}

// ---------------------------------------------------------------------------
extern "C" void kernel_launch(void* const* d_in, const int* in_sizes, int n_in,
                              void* d_out, int out_size, void* d_ws, size_t ws_size,
                              hipStream_t stream) {
  (void)in_sizes; (void)n_in; (void)out_size; (void)ws_size;
  const float* pattern = (const float*)d_in[0];
  const float* value   = (const float*)d_in[1];
  const float* Wq1 = (const float*)d_in[3];
  const float* bq1 = (const float*)d_in[4];
  const float* Wq2 = (const float*)d_in[5];
  const float* bq2 = (const float*)d_in[6];
  const float* Wk1 = (const float*)d_in[7];
  const float* bk1 = (const float*)d_in[8];
  const float* Wk2 = (const float*)d_in[9];
  const float* bk2 = (const float*)d_in[10];
  const float* Wo1 = (const float*)d_in[11];
  const float* bo1 = (const float*)d_in[12];
  const float* Wo2 = (const float*)d_in[13];
  const float* bo2 = (const float*)d_in[14];

  float* ws     = (float*)d_ws;
  float* A      = ws + A_OFF;
  float* c      = ws + C_OFF;
  float* meanv  = ws + MEAN_OFF;
  u16*   Aqk_bf = (u16*)(ws + AQKBF_OFF);
  u16*   Ao_bf  = (u16*)(ws + AOBF_OFF);
  u16*   qT     = (u16*)(ws + QT_OFF);
  u16*   kT     = (u16*)(ws + KT_OFF);
  u16*   vB     = (u16*)(ws + VB_OFF);
  float* out    = (float*)d_out;

  fuse_weights_all<<<384 + 512, 128, 0, stream>>>(
      Wq1, bq1, Wq2, bq2, Wk1, bk1, Wk2, bk2, Wo1, bo1, Wo2, bo2,
      A, c, Aqk_bf, Ao_bf, value, vB, meanv);

  prep_kernel<<<B_ * 64, 256, 0, stream>>>(pattern, Aqk_bf, c, qT, kT);

  // LDS: ks dbuf 69632 + vs dbuf 69632 + dls 512 = 139776 B -> 1 block/CU
  size_t lds_bytes = (size_t)(2 * 128 * QSTR + 2 * 128 * VSTR) * 2 + 128 * 4;
  attn_mfma_kernel<<<dim3(T_ / 128, B_), 512, lds_bytes, stream>>>(
      qT, kT, vB, Ao_bf, c + 256, A, meanv, out);
}

// Round 12
// 186.054 us; speedup vs baseline: 1.1004x; 1.0153x over previous
//
#include <hip/hip_runtime.h>
#include <hip/hip_bf16.h>
#include <math.h>

#define B_    16
#define M_    128
#define T_    2048
#define H_    512
#define TOUT_ 2049

typedef unsigned short u16;
typedef unsigned int   u32;
typedef __bf16 bf16x8 __attribute__((ext_vector_type(8)));
typedef float  f32x16 __attribute__((ext_vector_type(16)));
typedef float  f32x4  __attribute__((ext_vector_type(4)));
typedef u32    u32x4  __attribute__((ext_vector_type(4)));
typedef u32    u32x2  __attribute__((ext_vector_type(2)));

// ws layout (float units):
#define A_OFF     0                       // fp32 Ao only [128][128]
#define C_OFF     16384                   // c[3][128]
#define MEAN_OFF  16896                   // meanv [2048]
#define AQKBF_OFF 19200                   // u16 [256][128] = 16384 fl
#define AOBF_OFF  35584                   // u16 [128][128] = 8192 fl
#define QT_OFF    43776
#define KT_OFF    (43776 + 2097152)
#define VB_OFF    (43776 + 2 * 2097152)

static __device__ __forceinline__ u16 f2bf(float f) {
  u32 u = __float_as_uint(f);
  u = (u + 0x7FFFu + ((u >> 16) & 1u)) >> 16;
  return (u16)u;
}
static __device__ __forceinline__ u32 pk2(float lo, float hi) {
  __hip_bfloat162 h = __float22bfloat162_rn(float2{lo, hi});
  u32 r;
  __builtin_memcpy(&r, &h, 4);
  return r;
}
static __device__ __forceinline__ bf16x8 ldfrag(const u16* p) {
  return __builtin_bit_cast(bf16x8, *(const u32x4*)p);
}
static __device__ __forceinline__ float ex2(float x) {
#if __has_builtin(__builtin_amdgcn_exp2f)
  return __builtin_amdgcn_exp2f(x);  // v_exp_f32 = 2^x
#else
  return exp2f(x);
#endif
}

// ---------------------------------------------------------------------------
// fuse: blocks [0,384) = weight fusion; blocks [384,896) = value cast +
// windowed mean, ONE WAVE PER 2 ROWS, shuffle-reduce only (no barriers).
__global__ __launch_bounds__(128) void fuse_weights_all(
    const float* __restrict__ W1q, const float* __restrict__ b1q,
    const float* __restrict__ W2q, const float* __restrict__ b2q,
    const float* __restrict__ W1k, const float* __restrict__ b1k,
    const float* __restrict__ W2k, const float* __restrict__ b2k,
    const float* __restrict__ W1o, const float* __restrict__ b1o,
    const float* __restrict__ W2o, const float* __restrict__ b2o,
    float* __restrict__ A, float* __restrict__ c,
    u16* __restrict__ Aqk_bf, u16* __restrict__ Ao_bf,
    const float* __restrict__ value, u16* __restrict__ vb,
    float* __restrict__ meanv) {
  __shared__ float w2row[H_];
  int tid = threadIdx.x;

  if (blockIdx.x >= 384) {
    int bm0 = (blockIdx.x - 384) * 4;
    int w = tid >> 6, lane = tid & 63;
#pragma unroll
    for (int rr = 0; rr < 2; ++rr) {
      int bm = bm0 + w * 2 + rr;
      const float* row = value + (size_t)bm * T_;
      u16* vrow = vb + (size_t)bm * T_;
      float s = 0.f;
#pragma unroll
      for (int seg = 0; seg < 8; ++seg) {
        int col = seg * 256 + lane * 4;
        float4 a = *(const float4*)(row + col);
        u32x2 o = {pk2(a.x, a.y), pk2(a.z, a.w)};
        *(u32x2*)&vrow[col] = o;
        if (col >= 33 && col < T_ - 4) {
          s += ((a.x + a.y) + (a.z + a.w));
        } else {
          if (col + 0 >= 33 && col + 0 < T_ - 1) s += a.x;
          if (col + 1 >= 33 && col + 1 < T_ - 1) s += a.y;
          if (col + 2 >= 33 && col + 2 < T_ - 1) s += a.z;
          if (col + 3 >= 33 && col + 3 < T_ - 1) s += a.w;
        }
      }
#pragma unroll
      for (int off = 32; off > 0; off >>= 1) s += __shfl_down(s, off, 64);
      if (lane == 0) meanv[bm] = s * (1.f / 2014.f);
    }
    return;
  }

  int which = blockIdx.x >> 7;
  int o = blockIdx.x & 127;
  const float* W1 = which == 0 ? W1q : which == 1 ? W1k : W1o;
  const float* b1 = which == 0 ? b1q : which == 1 ? b1k : b1o;
  const float* W2 = which == 0 ? W2q : which == 1 ? W2k : W2o;
  const float* b2 = which == 0 ? b2q : which == 1 ? b2k : b2o;
  int m = tid;
  for (int h = m; h < H_; h += 128) w2row[h] = W2[o * H_ + h];
  __syncthreads();
  float acc = 0.f;
#pragma unroll 8
  for (int h = 0; h < H_; ++h) acc = fmaf(w2row[h], W1[h * M_ + m], acc);
  u16 ab = f2bf(acc);
  if (which == 0)      Aqk_bf[o * 128 + m] = ab;
  else if (which == 1) Aqk_bf[(128 + o) * 128 + m] = ab;
  else               { Ao_bf[o * 128 + m] = ab; A[o * M_ + m] = acc; }
  if (m < 64) {
    float cc = 0.f;
    for (int h = m; h < H_; h += 64) cc = fmaf(w2row[h], b1[h], cc);
#pragma unroll
    for (int off = 32; off > 0; off >>= 1) cc += __shfl_down(cc, off, 64);
    if (m == 0) c[which * 128 + o] = cc + b2[o];
  }
}

// ---------------------------------------------------------------------------
// prep v3: blocks [0,1024) = width-32 q/k MLP tiles (4 blocks/CU);
// blocks [1024,1040) = rep_ex tail (moved OFF attn's critical path --
// attn runs exactly 1 block/CU, so its 16 tail blocks extended the whole
// kernel; here they overlap prep's short blocks for free).
#define XS2 36

__global__ __launch_bounds__(256) void prep_kernel(
    const float* __restrict__ pattern, const u16* __restrict__ Aqk_bf,
    const float* __restrict__ cqk, u16* __restrict__ qT, u16* __restrict__ kT,
    const float* __restrict__ Aofp, const float* __restrict__ co,
    const float* __restrict__ meanv, float* __restrict__ out) {
  __shared__ alignas(16) float xsf[128 * XS2];  // 18432 B
  int bx = blockIdx.x;
  int tid = threadIdx.x;

  if (bx >= 1024) {
    // rep_ex tail: out[b][o][2048] = leaky(co[o] + sum_m A[o][m]*meanv[b][m])
    int b = bx - 1024;
    if (tid < 128) {
      int o = tid;
      const float* mv = meanv + b * 128;
      const float* arow = Aofp + o * 128;
      float a0 = 0.f, a1 = 0.f, a2 = 0.f, a3 = 0.f;
#pragma unroll 8
      for (int m = 0; m < 128; m += 4) {
        a0 = fmaf(arow[m + 0], mv[m + 0], a0);
        a1 = fmaf(arow[m + 1], mv[m + 1], a1);
        a2 = fmaf(arow[m + 2], mv[m + 2], a2);
        a3 = fmaf(arow[m + 3], mv[m + 3], a3);
      }
      float acc = co[o] + ((a0 + a1) + (a2 + a3));
      acc = acc > 0.f ? acc : 0.01f * acc;
      out[((size_t)(b * M_ + o)) * TOUT_ + 2048] = acc;
    }
    return;
  }

  int b = bx >> 6;
  int t0 = (bx & 63) * 32;
  int lane = tid & 63;
  int wv = tid >> 6;
  int l31 = lane & 31;
  int h = lane >> 5;
  int lh8 = h * 8;

  bf16x8 afr[2][8];
#pragma unroll
  for (int i = 0; i < 2; ++i) {
    const u16* ap = Aqk_bf + ((2 * wv + i) * 32 + l31) * 128 + lh8;
#pragma unroll
    for (int s = 0; s < 8; ++s) afr[i][s] = ldfrag(ap + 16 * s);
  }

  // stage pattern [128 m][32 t]
  {
    int m = tid >> 1;
    int cb = (tid & 1) * 16;
#pragma unroll
    for (int j = 0; j < 4; ++j) {
      float4 v = *(const float4*)&pattern[(size_t)(b * M_ + m) * T_ + t0 + cb + j * 4];
      *(float4*)&xsf[m * XS2 + cb + j * 4] = v;
    }
  }
  __syncthreads();

  bf16x8 bfr[8];
#pragma unroll
  for (int s = 0; s < 8; ++s) {
    float v0 = xsf[(s * 16 + lh8 + 0) * XS2 + l31];
    float v1 = xsf[(s * 16 + lh8 + 1) * XS2 + l31];
    float v2 = xsf[(s * 16 + lh8 + 2) * XS2 + l31];
    float v3 = xsf[(s * 16 + lh8 + 3) * XS2 + l31];
    float v4 = xsf[(s * 16 + lh8 + 4) * XS2 + l31];
    float v5 = xsf[(s * 16 + lh8 + 5) * XS2 + l31];
    float v6 = xsf[(s * 16 + lh8 + 6) * XS2 + l31];
    float v7 = xsf[(s * 16 + lh8 + 7) * XS2 + l31];
    u32x4 p = {pk2(v0, v1), pk2(v2, v3), pk2(v4, v5), pk2(v6, v7)};
    bfr[s] = __builtin_bit_cast(bf16x8, p);
  }
  __syncthreads();  // xsf dead -> obuf

  u16* obuf = (u16*)xsf;  // [32 t][258 o] u16 = 16512 B
  u32* ob32w = (u32*)xsf;
#pragma unroll
  for (int i = 0; i < 2; ++i) {
    f32x16 acc;
#pragma unroll
    for (int r = 0; r < 16; ++r) acc[r] = 0.f;
#pragma unroll
    for (int s = 0; s < 8; ++s)
      acc = __builtin_amdgcn_mfma_f32_32x32x16_bf16(afr[i][s], bfr[s], acc, 0, 0, 0);
    int ot = 2 * wv + i;
    int t = l31;
    float sc = (ot < 4) ? 1.44269504f : 1.0f;  // scale q (o<128) by log2e
#pragma unroll
    for (int g = 0; g < 4; ++g) {
      int orow0 = 8 * g + 4 * h;
      float q0 = acc[4 * g + 0] + cqk[ot * 32 + orow0 + 0];
      float q1 = acc[4 * g + 1] + cqk[ot * 32 + orow0 + 1];
      float q2 = acc[4 * g + 2] + cqk[ot * 32 + orow0 + 2];
      float q3 = acc[4 * g + 3] + cqk[ot * 32 + orow0 + 3];
      q0 = (q0 > 0.f ? q0 : 0.01f * q0) * sc;
      q1 = (q1 > 0.f ? q1 : 0.01f * q1) * sc;
      q2 = (q2 > 0.f ? q2 : 0.01f * q2) * sc;
      q3 = (q3 > 0.f ? q3 : 0.01f * q3) * sc;
      int u16i = t * 258 + ot * 32 + orow0;  // even
      ob32w[(u16i >> 1) + 0] = pk2(q0, q1);
      ob32w[(u16i >> 1) + 1] = pk2(q2, q3);
    }
  }
  __syncthreads();

  const u32* ob32 = (const u32*)obuf;
  {
    int t = tid >> 3;
#pragma unroll
    for (int j = 0; j < 4; ++j) {
      int qd = (tid & 7) * 4 + j;      // u32-quad index 0..31 (128 u32/row)
      int base = t * 129 + qd * 4;
      u32x4 vv = {ob32[base], ob32[base + 1], ob32[base + 2], ob32[base + 3]};
      int mat = qd >> 4;
      u32* dst = (u32*)((mat ? kT : qT) + ((size_t)(b * T_ + t0 + t)) * 128)
               + (qd & 15) * 4;
      *(u32x4*)dst = vv;
    }
  }
}

// ---------------------------------------------------------------------------
// attn v8.1: best-known v8 structure (59.1 us R11) with the rep_ex tail
// removed (now in prep -- it extended the 1-block/CU critical path here).
// 128-q blocks, 512 thr; 128-k tiles (NKT=16), Q frags from global,
// exp2-prescaled double-exp, setprio around MFMA clusters.
// Waves: qt = wv&3 (32 q's), kh = wv>>2 (64-k half of the 128-k tile).
#define QSTR 136  // u16: 68 words == 4 mod 32 (conflict-free)
#define VSTR 136
#define KTILE 128
#define NKT  (T_ / KTILE)
#define CINIT 0.52876637f   // log2(log2 e)

__global__ __launch_bounds__(512, 2) void attn_mfma_kernel(
    const u16* __restrict__ qT, const u16* __restrict__ kT,
    const u16* __restrict__ vB, const u16* __restrict__ Ao_bf,
    const float* __restrict__ co, float* __restrict__ out) {
  extern __shared__ u16 smem[];
  u16* ks0 = smem;                        // [128][QSTR] x2 (dbuf)
  u16* ks1 = ks0 + 128 * QSTR;
  u16* vs0 = ks1 + 128 * QSTR;            // [128][VSTR] x2 (dbuf)
  u16* vs1 = vs0 + 128 * VSTR;
  float* dls  = (float*)(vs1 + 128 * VSTR);  // [128]
  float* pbuf = (float*)ks0;              // 64 KB epilogue alias (ks dead)
  u16*   ptbuf = vs0;                     // [128][QSTR] epilogue alias (vs dead)

  int b = blockIdx.y;
  int q0 = blockIdx.x * 128;
  int tid = threadIdx.x;
  int lane = tid & 63;
  int wv = tid >> 6;                 // 0..7
  int l31 = lane & 31;
  int h = lane >> 5;
  int lh8 = h * 8;
  int qt = wv & 3;                   // q-tile (32 q's)
  int kh = wv >> 2;                  // 64-k half of 128-k tile

  const u16* gkb = kT + (size_t)b * T_ * 128;
  const u16* gvb = vB + (size_t)b * M_ * T_;
  int kr = tid >> 4, kc = (tid & 15) * 8;   // 32 rows/iter, 4 iters

  // persistent Q B-frags straight from global (one-time, L2-resident)
  bf16x8 qfrag[8];
  {
    const u16* qrow = qT + (size_t)(b * T_ + q0 + qt * 32 + l31) * 128 + lh8;
#pragma unroll
    for (int s = 0; s < 8; ++s) qfrag[s] = ldfrag(qrow + s * 16);
  }

  u32x4 kreg[4], vreg[4];
#pragma unroll
  for (int it = 0; it < 4; ++it) {
    kreg[it] = *(const u32x4*)&gkb[(size_t)(it * 32 + kr) * 128 + kc];
    vreg[it] = *(const u32x4*)&gvb[(size_t)(it * 32 + kr) * T_ + kc];
  }
  // write tile 0, load tile 1
#pragma unroll
  for (int it = 0; it < 4; ++it) {
    *(u32x4*)&ks0[(it * 32 + kr) * QSTR + kc] = kreg[it];
    *(u32x4*)&vs0[(it * 32 + kr) * VSTR + kc] = vreg[it];
  }
#pragma unroll
  for (int it = 0; it < 4; ++it) {
    kreg[it] = *(const u32x4*)&gkb[(size_t)(KTILE + it * 32 + kr) * 128 + kc];
    vreg[it] = *(const u32x4*)&gvb[(size_t)(it * 32 + kr) * T_ + KTILE + kc];
  }

  f32x16 pacc[4];
  float den = 0.f;
#pragma unroll
  for (int i = 0; i < 16; ++i) {
    pacc[0][i] = 0.f; pacc[1][i] = 0.f; pacc[2][i] = 0.f; pacc[3][i] = 0.f;
  }

  for (int kt = 0; kt < NKT; ++kt) {
    int k0 = kt * KTILE;
    u16* kcur = (kt & 1) ? ks1 : ks0;
    u16* knxt = (kt & 1) ? ks0 : ks1;
    u16* vcur = (kt & 1) ? vs1 : vs0;
    u16* vnxt = (kt & 1) ? vs0 : vs1;
    __syncthreads();  // [T] tile-kt staging visible; prev readers drained

    // S'[k][q] = mfma(K, Q) over this wave's 64 k's (2 x 32-row subtiles)
    f32x16 sacc_a, sacc_b;
#pragma unroll
    for (int i = 0; i < 16; ++i) { sacc_a[i] = CINIT; sacc_b[i] = CINIT; }
    {
      const u16* krowa = &kcur[(kh * 64 + l31) * QSTR + lh8];
      const u16* krowb = krowa + 32 * QSTR;
      __builtin_amdgcn_s_setprio(1);
#pragma unroll
      for (int s = 0; s < 8; ++s) {
        bf16x8 kfa = ldfrag(krowa + s * 16);
        sacc_a = __builtin_amdgcn_mfma_f32_32x32x16_bf16(kfa, qfrag[s], sacc_a, 0, 0, 0);
      }
#pragma unroll
      for (int s = 0; s < 8; ++s) {
        bf16x8 kfb = ldfrag(krowb + s * 16);
        sacc_b = __builtin_amdgcn_mfma_f32_32x32x16_bf16(kfb, qfrag[s], sacc_b, 0, 0, 0);
      }
      __builtin_amdgcn_s_setprio(0);
    }

    // stage tile kt+1 into nxt buffers; prefetch tile kt+2
    if (kt < NKT - 1) {
#pragma unroll
      for (int it = 0; it < 4; ++it) {
        *(u32x4*)&knxt[(it * 32 + kr) * QSTR + kc] = kreg[it];
        *(u32x4*)&vnxt[(it * 32 + kr) * VSTR + kc] = vreg[it];
      }
      int kn = (kt + 2 < NKT) ? (kt + 2) * KTILE : (NKT - 1) * KTILE;
#pragma unroll
      for (int it = 0; it < 4; ++it) {
        kreg[it] = *(const u32x4*)&gkb[(size_t)(kn + it * 32 + kr) * 128 + kc];
        vreg[it] = *(const u32x4*)&gvb[(size_t)(it * 32 + kr) * T_ + kn + kc];
      }
    }

    // diagonal adjust (scaled domain): x -> x*d + C*(1-d)
    if (k0 + kh * 64 == q0 + qt * 32) {
#pragma unroll
      for (int r = 0; r < 16; ++r) {
        int row = (r & 3) + 8 * (r >> 2) + 4 * h;
        if (row == l31) sacc_a[r] = fmaf(sacc_a[r], 0.97790291f, 0.01168420f);
      }
    } else if (k0 + kh * 64 + 32 == q0 + qt * 32) {
#pragma unroll
      for (int r = 0; r < 16; ++r) {
        int row = (r & 3) + 8 * (r >> 2) + 4 * h;
        if (row == l31) sacc_b[r] = fmaf(sacc_b[r], 0.97790291f, 0.01168420f);
      }
    }

    // ---- half A: w = exp2(exp2(s)), pack, exchange, PV slices 0,1 ----
    {
      float w[16];
#pragma unroll
      for (int r = 0; r < 16; ++r) w[r] = ex2(ex2(sacc_a[r]));
      float d0 = (w[0] + w[1]) + (w[2] + w[3]);
      float d1 = (w[4] + w[5]) + (w[6] + w[7]);
      float d2 = (w[8] + w[9]) + (w[10] + w[11]);
      float d3 = (w[12] + w[13]) + (w[14] + w[15]);
      den += (d0 + d1) + (d2 + d3);
      u32 p00 = pk2(w[0], w[1]),  p01 = pk2(w[2], w[3]);
      u32 p10 = pk2(w[4], w[5]),  p11 = pk2(w[6], w[7]);
      u32 p20 = pk2(w[8], w[9]),  p21 = pk2(w[10], w[11]);
      u32 p30 = pk2(w[12], w[13]), p31 = pk2(w[14], w[15]);
      u32 e0 = __shfl_xor(h ? p00 : p10, 32, 64);
      u32 e1 = __shfl_xor(h ? p01 : p11, 32, 64);
      u32 e2 = __shfl_xor(h ? p20 : p30, 32, 64);
      u32 e3 = __shfl_xor(h ? p21 : p31, 32, 64);
      u32x4 f0 = h ? u32x4{e0, e1, p10, p11} : u32x4{p00, p01, e0, e1};
      u32x4 f1 = h ? u32x4{e2, e3, p30, p31} : u32x4{p20, p21, e2, e3};
      bf16x8 bw0 = __builtin_bit_cast(bf16x8, f0);
      bf16x8 bw1 = __builtin_bit_cast(bf16x8, f1);
      __builtin_amdgcn_s_setprio(1);
#pragma unroll
      for (int mt = 0; mt < 4; ++mt) {
        const u16* vrow = &vcur[(mt * 32 + l31) * VSTR + kh * 64 + lh8];
        bf16x8 vf0 = ldfrag(vrow);
        bf16x8 vf1 = ldfrag(vrow + 16);
        pacc[mt] = __builtin_amdgcn_mfma_f32_32x32x16_bf16(vf0, bw0, pacc[mt], 0, 0, 0);
        pacc[mt] = __builtin_amdgcn_mfma_f32_32x32x16_bf16(vf1, bw1, pacc[mt], 0, 0, 0);
      }
      __builtin_amdgcn_s_setprio(0);
    }
    // ---- half B: slices 2,3 ----
    {
      float w[16];
#pragma unroll
      for (int r = 0; r < 16; ++r) w[r] = ex2(ex2(sacc_b[r]));
      float d0 = (w[0] + w[1]) + (w[2] + w[3]);
      float d1 = (w[4] + w[5]) + (w[6] + w[7]);
      float d2 = (w[8] + w[9]) + (w[10] + w[11]);
      float d3 = (w[12] + w[13]) + (w[14] + w[15]);
      den += (d0 + d1) + (d2 + d3);
      u32 p00 = pk2(w[0], w[1]),  p01 = pk2(w[2], w[3]);
      u32 p10 = pk2(w[4], w[5]),  p11 = pk2(w[6], w[7]);
      u32 p20 = pk2(w[8], w[9]),  p21 = pk2(w[10], w[11]);
      u32 p30 = pk2(w[12], w[13]), p31 = pk2(w[14], w[15]);
      u32 e0 = __shfl_xor(h ? p00 : p10, 32, 64);
      u32 e1 = __shfl_xor(h ? p01 : p11, 32, 64);
      u32 e2 = __shfl_xor(h ? p20 : p30, 32, 64);
      u32 e3 = __shfl_xor(h ? p21 : p31, 32, 64);
      u32x4 f0 = h ? u32x4{e0, e1, p10, p11} : u32x4{p00, p01, e0, e1};
      u32x4 f1 = h ? u32x4{e2, e3, p30, p31} : u32x4{p20, p21, e2, e3};
      bf16x8 bw2 = __builtin_bit_cast(bf16x8, f0);
      bf16x8 bw3 = __builtin_bit_cast(bf16x8, f1);
      __builtin_amdgcn_s_setprio(1);
#pragma unroll
      for (int mt = 0; mt < 4; ++mt) {
        const u16* vrow = &vcur[(mt * 32 + l31) * VSTR + kh * 64 + 32 + lh8];
        bf16x8 vf2 = ldfrag(vrow);
        bf16x8 vf3 = ldfrag(vrow + 16);
        pacc[mt] = __builtin_amdgcn_mfma_f32_32x32x16_bf16(vf2, bw2, pacc[mt], 0, 0, 0);
        pacc[mt] = __builtin_amdgcn_mfma_f32_32x32x16_bf16(vf3, bw3, pacc[mt], 0, 0, 0);
      }
      __builtin_amdgcn_s_setprio(0);
    }
  }

  // per-q denominator for this k-half (lane q = l31, both h halves summed)
  float dq = den + __shfl_xor(den, 32, 64);

  __syncthreads();  // [E1] all PV reads of ks/vs done -> aliases safe

  if (kh == 1) {
#pragma unroll
    for (int mt = 0; mt < 4; ++mt) {
      float* pb = &pbuf[((size_t)(qt * 4 + mt) * 64 + lane) * 16];
#pragma unroll
      for (int g = 0; g < 4; ++g) {
        f32x4 v = {pacc[mt][4 * g], pacc[mt][4 * g + 1],
                   pacc[mt][4 * g + 2], pacc[mt][4 * g + 3]};
        *(f32x4*)(pb + 4 * g) = v;
      }
    }
    if (lane < 32) dls[qt * 32 + lane] = dq;
  }
  __syncthreads();  // [E2]

  if (kh == 0) {
    float rden = 1.f / (dq + dls[qt * 32 + l31]);
#pragma unroll
    for (int mt = 0; mt < 4; ++mt) {
      const float* pb = &pbuf[((size_t)(qt * 4 + mt) * 64 + lane) * 16];
#pragma unroll
      for (int g = 0; g < 4; ++g) {
        f32x4 t = *(const f32x4*)(pb + 4 * g);
        float v0 = (pacc[mt][4 * g + 0] + t[0]) * rden;
        float v1 = (pacc[mt][4 * g + 1] + t[1]) * rden;
        float v2 = (pacc[mt][4 * g + 2] + t[2]) * rden;
        float v3 = (pacc[mt][4 * g + 3] + t[3]) * rden;
        int m0 = mt * 32 + 8 * g + 4 * h;
        u32x2 wp = {pk2(v0, v1), pk2(v2, v3)};
        *(u32x2*)&ptbuf[(qt * 32 + l31) * QSTR + m0] = wp;
      }
    }
  }
  __syncthreads();  // [E3] P^T visible

  // o-MLP epilogue: wave wv -> o-tile (wv&3), q-tiles {2*kh, 2*kh+1}
  bf16x8 aofr[8];
  {
    const u16* ap = Ao_bf + ((wv & 3) * 32 + l31) * 128 + lh8;
#pragma unroll
    for (int s = 0; s < 8; ++s) aofr[s] = ldfrag(ap + 16 * s);
  }
#pragma unroll
  for (int j = 0; j < 2; ++j) {
    int qt2 = kh * 2 + j;
    bf16x8 pfr[8];
    const u16* pp = &ptbuf[(qt2 * 32 + l31) * QSTR + lh8];
#pragma unroll
    for (int s = 0; s < 8; ++s) pfr[s] = ldfrag(pp + 16 * s);
    f32x16 oacc;
#pragma unroll
    for (int r = 0; r < 16; ++r) oacc[r] = 0.f;
#pragma unroll
    for (int s = 0; s < 8; ++s)
      oacc = __builtin_amdgcn_mfma_f32_32x32x16_bf16(aofr[s], pfr[s], oacc, 0, 0, 0);
#pragma unroll
    for (int r = 0; r < 16; ++r) {
      int orow = (wv & 3) * 32 + (r & 3) + 8 * (r >> 2) + 4 * h;
      float v = oacc[r] + co[orow];
      v = v > 0.f ? v : 0.01f * v;
      out[((size_t)(b * M_ + orow)) * TOUT_ + q0 + qt2 * 32 + l31] = v;
    }
  }
}

// ---------------------------------------------------------------------------
extern "C" void kernel_launch(void* const* d_in, const int* in_sizes, int n_in,
                              void* d_out, int out_size, void* d_ws, size_t ws_size,
                              hipStream_t stream) {
  (void)in_sizes; (void)n_in; (void)out_size; (void)ws_size;
  const float* pattern = (const float*)d_in[0];
  const float* value   = (const float*)d_in[1];
  const float* Wq1 = (const float*)d_in[3];
  const float* bq1 = (const float*)d_in[4];
  const float* Wq2 = (const float*)d_in[5];
  const float* bq2 = (const float*)d_in[6];
  const float* Wk1 = (const float*)d_in[7];
  const float* bk1 = (const float*)d_in[8];
  const float* Wk2 = (const float*)d_in[9];
  const float* bk2 = (const float*)d_in[10];
  const float* Wo1 = (const float*)d_in[11];
  const float* bo1 = (const float*)d_in[12];
  const float* Wo2 = (const float*)d_in[13];
  const float* bo2 = (const float*)d_in[14];

  float* ws     = (float*)d_ws;
  float* A      = ws + A_OFF;
  float* c      = ws + C_OFF;
  float* meanv  = ws + MEAN_OFF;
  u16*   Aqk_bf = (u16*)(ws + AQKBF_OFF);
  u16*   Ao_bf  = (u16*)(ws + AOBF_OFF);
  u16*   qT     = (u16*)(ws + QT_OFF);
  u16*   kT     = (u16*)(ws + KT_OFF);
  u16*   vB     = (u16*)(ws + VB_OFF);
  float* out    = (float*)d_out;

  fuse_weights_all<<<384 + 512, 128, 0, stream>>>(
      Wq1, bq1, Wq2, bq2, Wk1, bk1, Wk2, bk2, Wo1, bo1, Wo2, bo2,
      A, c, Aqk_bf, Ao_bf, value, vB, meanv);

  prep_kernel<<<B_ * 64 + B_, 256, 0, stream>>>(
      pattern, Aqk_bf, c, qT, kT, A, c + 256, meanv, out);

  // LDS: ks dbuf 69632 + vs dbuf 69632 + dls 512 = 139776 B -> 1 block/CU
  size_t lds_bytes = (size_t)(2 * 128 * QSTR + 2 * 128 * VSTR) * 2 + 128 * 4;
  attn_mfma_kernel<<<dim3(T_ / 128, B_), 512, lds_bytes, stream>>>(
      qT, kT, vB, Ao_bf, c + 256, out);
}